// Round 9
// baseline (377.025 us; speedup 1.0000x reference)
//
#include <hip/hip_runtime.h>
#include <stdint.h>

#define N_NODES 100000
#define N_EDGES 1600000
#define NBLK_SCAN 391   // ceil(N_NODES/256)

typedef __attribute__((ext_vector_type(8))) short short8;
typedef __attribute__((ext_vector_type(4))) float float4v;

__device__ __forceinline__ unsigned short f32_to_bf16(float f) {
  uint32_t u = __float_as_uint(f);
  u += 0x7fffu + ((u >> 16) & 1u);   // RNE
  return (unsigned short)(u >> 16);
}
__device__ __forceinline__ float bf16_to_f32(unsigned short h) {
  return __uint_as_float(((uint32_t)h) << 16);
}

// ---------------------------------------------------------------------------
// K_zero: deg=0; build wbf = 52 MFMA A-fragment tiles (TRANSPOSED scheme:
// A = W^T so D rows = features, D cols = nodes):
//   tiles 0..49 : A[row=fo_local][k=fin] = weight[km=t>>1][fin][(t&1)*16+row]
//   tiles 50,51 : root_w^T
// slot((t,q,row,j)) = t*512 + q*128 + row*8 + j,  fin = q*8+j.
// ---------------------------------------------------------------------------
__global__ __launch_bounds__(256) void k_zero(
    const float* __restrict__ weight, const float* __restrict__ root_w,
    int* __restrict__ deg, unsigned short* __restrict__ wbf) {
  int tid = threadIdx.x;
  int b = blockIdx.x;
  int i = b * 256 + tid;
  if (i < N_NODES) deg[i] = 0;
  if (b < 100) {            // 25600 weight-tile slots
    int e = i;
    int t = e >> 9, rem = e & 511;
    int q = rem >> 7, row = (rem >> 3) & 15, j = rem & 7;
    int km = t >> 1, fin = q * 8 + j, fo = (t & 1) * 16 + row;
    wbf[e] = f32_to_bf16(weight[(km * 32 + fin) * 32 + fo]);
  } else if (b == 100) {    // root tiles 50,51
    for (int idx = tid; idx < 1024; idx += 256) {
      int t = 50 + (idx >> 9), rem = idx & 511;
      int q = rem >> 7, row = (rem >> 3) & 15, j = rem & 7;
      int fin = q * 8 + j, fo = (t - 50) * 16 + row;
      wbf[t * 512 + rem] = f32_to_bf16(root_w[fin * 32 + fo]);
    }
  }
}

// ---------------------------------------------------------------------------
// K1 (6250 blocks, 16 nodes each) — fused hist + transposed MFMA:
//  - hist: NON-RETURNING atomicAdd(&deg[ei[e]],1) (fire-and-forget; the
//    round-8 version kept the return for rank — that dependency + churn is
//    gone; rank assignment moved to kscatter's cursor atomic).
//  - 52 tiles = 4 waves x 13: perfectly uniform loop.
//  - D[fo][node]: lane packs 4 consecutive features of one node as uint2,
//    staged in LDS at swizzled slot tq*16 + (node ^ (tq&15)); copy-out is
//    25.6 KB of linear global per block via NON-TEMPORAL 8B stores (xw is
//    160 MB — it cannot live in L2 until k2; keep L2 for deg/atomics).
//  - tiles 50,51 (wave 3, in-loop): out = x_root + bias; r_dot -> od[].y
// ---------------------------------------------------------------------------
__global__ __launch_bounds__(256) void k1_xw(
    const float* __restrict__ x, const unsigned short* __restrict__ wbf,
    const int* __restrict__ ei, const float* __restrict__ att_w,
    const float* __restrict__ bias,
    int* __restrict__ deg,
    unsigned short* __restrict__ xw, float* __restrict__ out,
    uint2* __restrict__ od) {
  __shared__ __align__(16) uint2 st[3200];   // 25.6 KB: tiles 0..49
  int tid = threadIdx.x;
  int b = blockIdx.x;

  int e = b * 256 + tid;
  atomicAdd(&deg[ei[e]], 1);   // result unused -> non-returning atomic

  int wave = tid >> 6, lane = tid & 63;
  int quad = lane >> 4, c16 = lane & 15;
  int n0 = b * 16;
  int node = n0 + c16;
  // B-fragment = x^T: lane holds x[node=c16][fin = quad*8 + j]
  const float* xp = x + (size_t)node * 32 + quad * 8;
  float4 a0 = *reinterpret_cast<const float4*>(xp);
  float4 a1 = *reinterpret_cast<const float4*>(xp + 4);
  short8 af;
  af[0] = (short)f32_to_bf16(a0.x); af[1] = (short)f32_to_bf16(a0.y);
  af[2] = (short)f32_to_bf16(a0.z); af[3] = (short)f32_to_bf16(a0.w);
  af[4] = (short)f32_to_bf16(a1.x); af[5] = (short)f32_to_bf16(a1.y);
  af[6] = (short)f32_to_bf16(a1.z); af[7] = (short)f32_to_bf16(a1.w);

  float rsum = 0.f;
  for (int idx = 0; idx < 13; idx++) {
    int t = wave * 13 + idx;
    // A-fragment: lane holds A[row=c16][k=quad*8+j]
    short8 bf = *reinterpret_cast<const short8*>(wbf + ((t * 4 + quad) * 16 + c16) * 8);
    float4v acc = {0.f, 0.f, 0.f, 0.f};
    acc = __builtin_amdgcn_mfma_f32_16x16x32_bf16(bf, af, acc, 0, 0, 0);
    // D: col=lane&15=node, row=quad*4+r = fo_local
    if (t < 50) {
      uint2 pk;
      pk.x = (unsigned int)f32_to_bf16(acc[0]) |
             ((unsigned int)f32_to_bf16(acc[1]) << 16);
      pk.y = (unsigned int)f32_to_bf16(acc[2]) |
             ((unsigned int)f32_to_bf16(acc[3]) << 16);
      int tq = t * 4 + quad;
      st[tq * 16 + (c16 ^ (tq & 15))] = pk;
    } else {               // wave 3 only: tiles 50,51
      int gfo = (t - 50) * 16 + quad * 4;
      float4 bi = *reinterpret_cast<const float4*>(bias + gfo);
      float4 o;
      o.x = acc[0] + bi.x; o.y = acc[1] + bi.y;
      o.z = acc[2] + bi.z; o.w = acc[3] + bi.w;
      *reinterpret_cast<float4*>(out + (size_t)node * 32 + gfo) = o;
      float4 aw = *reinterpret_cast<const float4*>(att_w + gfo);
      rsum += acc[0] * aw.x + acc[1] * aw.y + acc[2] * aw.z + acc[3] * aw.w;
    }
  }
  if (wave == 3) {   // wave 3 owned both root tiles -> full r_dot
    rsum += __shfl_xor(rsum, 16);
    rsum += __shfl_xor(rsum, 32);
    if (lane < 16) od[node].y = __float_as_uint(rsum);
  }
  __syncthreads();
  // copy-out: dst is 3200 CONSECUTIVE uint2 (block writes 25.6 KB linear),
  // non-temporal 8B stores (512 B per wave-instr).
  unsigned long long* dst =
      reinterpret_cast<unsigned long long*>(xw) + (size_t)n0 * 200;
  const unsigned long long* stq =
      reinterpret_cast<const unsigned long long*>(st);
  for (int j = tid; j < 3200; j += 256) {
    int nd = j / 200;
    int tq = j - nd * 200;
    __builtin_nontemporal_store(stq[tq * 16 + (nd ^ (tq & 15))], dst + j);
  }
}

// ---------------------------------------------------------------------------
// 3-kernel exclusive scan of deg -> {od[].x, cur}.
// ---------------------------------------------------------------------------
__global__ __launch_bounds__(256) void kscan1(const int* __restrict__ deg,
                                              int* __restrict__ incl,
                                              int* __restrict__ bsum) {
  __shared__ int s[256];
  int tid = threadIdx.x;
  int i = blockIdx.x * 256 + tid;
  int v = (i < N_NODES) ? deg[i] : 0;
  s[tid] = v;
  __syncthreads();
  for (int d = 1; d < 256; d <<= 1) {
    int t = (tid >= d) ? s[tid - d] : 0;
    __syncthreads();
    s[tid] += t;
    __syncthreads();
  }
  if (i < N_NODES) incl[i] = s[tid];
  if (tid == 255) bsum[blockIdx.x] = s[255];
}

__global__ __launch_bounds__(512) void kscan2(const int* __restrict__ bsum,
                                              int* __restrict__ bbase) {
  __shared__ int s[512];
  int tid = threadIdx.x;
  int v = (tid < NBLK_SCAN) ? bsum[tid] : 0;
  s[tid] = v;
  __syncthreads();
  for (int d = 1; d < 512; d <<= 1) {
    int t = (tid >= d) ? s[tid - d] : 0;
    __syncthreads();
    s[tid] += t;
    __syncthreads();
  }
  if (tid < NBLK_SCAN) bbase[tid] = s[tid] - v;  // exclusive
}

__global__ __launch_bounds__(256) void kscan3(const int* __restrict__ deg,
                                              const int* __restrict__ incl,
                                              const int* __restrict__ bbase,
                                              uint2* __restrict__ od,
                                              int* __restrict__ cur) {
  int i = blockIdx.x * 256 + threadIdx.x;
  if (i < N_NODES) {
    int v = incl[i] - deg[i] + bbase[i >> 8];
    od[i].x = (unsigned int)v;   // exclusive offset, packed next to r_dot
    cur[i] = v;                  // kscatter's allocation cursor
  }
  if (i == 0) od[N_NODES].x = (unsigned int)N_EDGES;  // k2 reads od[node+1].x
}

// ---------------------------------------------------------------------------
// K_scatter: 1 edge/thread, 6250 blocks. pos = atomicAdd(&cur[r],1) —
// rank array deleted (k1's atomic is now non-returning; the returning
// atomic lives here where 25K waves hide its latency). Within-segment
// order becomes nondeterministic; k2 only sums over the segment.
//   epack.x = col*800 + w0*32  (direct xw element offset, 27 bits;
//             w2 = w0+5 always -> k2 uses +160/+192)
//   epack.y = fr0_q16 | fr1_q16<<16
// ---------------------------------------------------------------------------
__global__ __launch_bounds__(256) void kscatter(
    const int* __restrict__ ei, const float* __restrict__ pseudo,
    int* __restrict__ cur, uint2* __restrict__ epack) {
  int e = blockIdx.x * 256 + threadIdx.x;
  int r = ei[e];
  int c = ei[N_EDGES + e];
  float p0 = pseudo[2 * e] * 4.f;
  float p1 = pseudo[2 * e + 1] * 4.f;
  float fl0 = floorf(p0), fl1 = floorf(p1);
  float fr0 = p0 - fl0, fr1 = p1 - fl1;
  int i0 = (int)fl0, i1 = (int)fl1;
  int w0 = i0 + 5 * i1;
  unsigned int q0 = (unsigned int)(fr0 * 65535.f + 0.5f);
  unsigned int q1 = (unsigned int)(fr1 * 65535.f + 0.5f);
  int pos = atomicAdd(&cur[r], 1);
  uint2 pk;
  pk.x = (unsigned int)(c * 800 + w0 * 32);
  pk.y = q0 | (q1 << 16);
  epack[pos] = pk;
}

// ---------------------------------------------------------------------------
// K2: one wave per node; halves process alternate edges (lane=f_out);
// 4-deep unroll per half. alpha inline: msg from 4 xw gathers at
// base[0],[32],[160],[192] (offset precomputed in epack.x), t = msg.att2
// via 5-step shfl_xor reduce, leaky-relu + exp, acc += msg*ex, den += ex.
// ---------------------------------------------------------------------------
__global__ __launch_bounds__(256) void k2_csr(
    const uint2* __restrict__ od, const uint2* __restrict__ epack,
    const unsigned short* __restrict__ xw, const float* __restrict__ att_w,
    float* __restrict__ out) {
  int tid = threadIdx.x;
  int wave = tid >> 6, lane = tid & 63;
  int node = blockIdx.x * 4 + wave;
  if (node >= N_NODES) return;
  int f = lane & 31, half = lane >> 5;
  uint2 v0 = od[node];
  int s0 = (int)v0.x;
  int s1 = (int)od[node + 1].x;
  float rd = __uint_as_float(v0.y);
  float a2 = att_w[32 + f];
  const unsigned short* xwf = xw + f;
  float acc = 0.f, den = 0.f;
  int i = s0 + half;
  const float Q = 1.f / 65535.f;

  for (; i + 6 < s1; i += 8) {
    uint2 p[4];
    p[0] = epack[i];     p[1] = epack[i + 2];
    p[2] = epack[i + 4]; p[3] = epack[i + 6];
    float fr0[4], fr1[4];
#pragma unroll
    for (int u = 0; u < 4; u++) {
      fr0[u] = (float)(p[u].y & 0xffff) * Q;
      fr1[u] = (float)(p[u].y >> 16) * Q;
    }
    float g0[4], g1[4], g2[4], g3[4];
#pragma unroll
    for (int u = 0; u < 4; u++) {
      const unsigned short* base = xwf + p[u].x;
      g0[u] = bf16_to_f32(base[0]);
      g1[u] = bf16_to_f32(base[32]);
      g2[u] = bf16_to_f32(base[160]);
      g3[u] = bf16_to_f32(base[192]);
    }
    float msg[4], t[4];
#pragma unroll
    for (int u = 0; u < 4; u++) {
      float c0 = 1.f - fr0[u], c1 = 1.f - fr1[u];
      msg[u] = c1 * (c0 * g0[u] + fr0[u] * g1[u]) +
               fr1[u] * (c0 * g2[u] + fr0[u] * g3[u]);
      t[u] = msg[u] * a2;
    }
#pragma unroll
    for (int m = 16; m >= 1; m >>= 1) {
      t[0] += __shfl_xor(t[0], m);
      t[1] += __shfl_xor(t[1], m);
      t[2] += __shfl_xor(t[2], m);
      t[3] += __shfl_xor(t[3], m);
    }
#pragma unroll
    for (int u = 0; u < 4; u++) {
      float alpha = rd + t[u];
      alpha = alpha > 0.f ? alpha : 0.2f * alpha;
      float ex = __expf(alpha);
      acc += msg[u] * ex;
      den += ex;
    }
  }
  for (; i < s1; i += 2) {
    uint2 pv = epack[i];
    float fr0 = (float)(pv.y & 0xffff) * Q;
    float fr1 = (float)(pv.y >> 16) * Q;
    const unsigned short* base = xwf + pv.x;
    float g0 = bf16_to_f32(base[0]);
    float g1 = bf16_to_f32(base[32]);
    float g2 = bf16_to_f32(base[160]);
    float g3 = bf16_to_f32(base[192]);
    float c0 = 1.f - fr0, c1 = 1.f - fr1;
    float msg = c1 * (c0 * g0 + fr0 * g1) + fr1 * (c0 * g2 + fr0 * g3);
    float t = msg * a2;
#pragma unroll
    for (int m = 16; m >= 1; m >>= 1) t += __shfl_xor(t, m);
    float alpha = rd + t;
    alpha = alpha > 0.f ? alpha : 0.2f * alpha;
    float ex = __expf(alpha);
    acc += msg * ex;
    den += ex;
  }

  acc += __shfl_xor(acc, 32);
  den += __shfl_xor(den, 32);
  if (half == 0) out[node * 32 + f] += acc / (den + 1e-16f);
}

extern "C" void kernel_launch(void* const* d_in, const int* in_sizes, int n_in,
                              void* d_out, int out_size, void* d_ws, size_t ws_size,
                              hipStream_t stream) {
  const float* x      = (const float*)d_in[0];
  const int*   ei     = (const int*)d_in[1];
  const float* pseudo = (const float*)d_in[2];
  const float* weight = (const float*)d_in[3];
  const float* root_w = (const float*)d_in[4];
  const float* att_w  = (const float*)d_in[5];
  const float* bias   = (const float*)d_in[6];
  float* out = (float*)d_out;

  char* ws = (char*)d_ws;
  unsigned short* xw   = (unsigned short*)ws;                 // 160,000,000 B
  uint2* od            = (uint2*)(ws + 160000000);            //     800,016 B {offs, r_dot} x (N+1)
  unsigned short* wbf  = (unsigned short*)(ws + 160800016);   //      53,248 B (52 tiles)
  int* deg             = (int*)(ws + 160853264);              //     400,000 B
  int* incl            = (int*)(ws + 161253264);              //     400,000 B
  int* cur             = (int*)(ws + 161653264);              //     400,000 B
  int* bsum            = (int*)(ws + 162053264);              //       1,600 B
  int* bbase           = (int*)(ws + 162054864);              //       1,600 B
  uint2* epack         = (uint2*)(ws + 162056464);            //  12,800,000 B -> 174.86 MB

  hipLaunchKernelGGL(k_zero, dim3(NBLK_SCAN), dim3(256), 0, stream,
                     weight, root_w, deg, wbf);
  hipLaunchKernelGGL(k1_xw, dim3(6250), dim3(256), 0, stream,
                     x, wbf, ei, att_w, bias, deg, xw, out, od);
  hipLaunchKernelGGL(kscan1, dim3(NBLK_SCAN), dim3(256), 0, stream, deg, incl, bsum);
  hipLaunchKernelGGL(kscan2, dim3(1), dim3(512), 0, stream, bsum, bbase);
  hipLaunchKernelGGL(kscan3, dim3(NBLK_SCAN), dim3(256), 0, stream,
                     deg, incl, bbase, od, cur);
  hipLaunchKernelGGL(kscatter, dim3(6250), dim3(256), 0, stream,
                     ei, pseudo, cur, epack);
  hipLaunchKernelGGL(k2_csr, dim3(25000), dim3(256), 0, stream,
                     od, epack, xw, att_w, out);
}

// Round 10
// 322.088 us; speedup vs baseline: 1.1706x; 1.1706x over previous
//
#include <hip/hip_runtime.h>
#include <stdint.h>

#define N_NODES 100000
#define N_EDGES 1600000
#define NBLK_SCAN 391   // ceil(N_NODES/256)

typedef __attribute__((ext_vector_type(8))) short short8;
typedef __attribute__((ext_vector_type(4))) float float4v;

__device__ __forceinline__ unsigned short f32_to_bf16(float f) {
  uint32_t u = __float_as_uint(f);
  u += 0x7fffu + ((u >> 16) & 1u);   // RNE
  return (unsigned short)(u >> 16);
}
__device__ __forceinline__ float bf16_to_f32(unsigned short h) {
  return __uint_as_float(((uint32_t)h) << 16);
}

// ---------------------------------------------------------------------------
// K_zero: deg=0; build wbf = 52 MFMA A-fragment tiles (TRANSPOSED scheme:
// A = W^T so D rows = features, D cols = nodes):
//   tiles 0..49 : A[row=fo_local][k=fin] = weight[km=t>>1][fin][(t&1)*16+row]
//   tiles 50,51 : root_w^T
// slot((t,q,row,j)) = t*512 + q*128 + row*8 + j,  fin = q*8+j.
// ---------------------------------------------------------------------------
__global__ __launch_bounds__(256) void k_zero(
    const float* __restrict__ weight, const float* __restrict__ root_w,
    int* __restrict__ deg, unsigned short* __restrict__ wbf) {
  int tid = threadIdx.x;
  int b = blockIdx.x;
  int i = b * 256 + tid;
  if (i < N_NODES) deg[i] = 0;
  if (b < 100) {            // 25600 weight-tile slots
    int e = i;
    int t = e >> 9, rem = e & 511;
    int q = rem >> 7, row = (rem >> 3) & 15, j = rem & 7;
    int km = t >> 1, fin = q * 8 + j, fo = (t & 1) * 16 + row;
    wbf[e] = f32_to_bf16(weight[(km * 32 + fin) * 32 + fo]);
  } else if (b == 100) {    // root tiles 50,51
    for (int idx = tid; idx < 1024; idx += 256) {
      int t = 50 + (idx >> 9), rem = idx & 511;
      int q = rem >> 7, row = (rem >> 3) & 15, j = rem & 7;
      int fin = q * 8 + j, fo = (t - 50) * 16 + row;
      wbf[t * 512 + rem] = f32_to_bf16(root_w[fin * 32 + fo]);
    }
  }
}

// ---------------------------------------------------------------------------
// K1 (6250 blocks, 16 nodes each) — fused hist + transposed MFMA
// (round-8 structure restored: returning atomic for rank, TEMPORAL stores —
//  round-9's nt-store/cursor bundle cost +44us: k2's achieved BW fell
//  3.6->2.9 TB/s with xw evicted from L2, and the kscatter cursor atomic
//  lost the MFMA overlap that k1 provides):
//  - hist: rank[e] = atomicAdd(&deg[ei[e]],1), stored at the end.
//  - 52 tiles = 4 waves x 13: perfectly uniform loop.
//  - D[fo][node]: lane packs 4 consecutive features of one node as uint2,
//    staged in LDS at swizzled slot tq*16 + (node ^ (tq&15)); copy-out is
//    25.6 KB of linear global per block (512 B per wave-instr).
//  - tiles 50,51 (wave 3, in-loop): out = x_root + bias; r_dot -> od[].y
// ---------------------------------------------------------------------------
__global__ __launch_bounds__(256) void k1_xw(
    const float* __restrict__ x, const unsigned short* __restrict__ wbf,
    const int* __restrict__ ei, const float* __restrict__ att_w,
    const float* __restrict__ bias,
    int* __restrict__ deg, unsigned short* __restrict__ rank,
    unsigned short* __restrict__ xw, float* __restrict__ out,
    uint2* __restrict__ od) {
  __shared__ __align__(16) uint2 st[3200];   // 25.6 KB: tiles 0..49
  int tid = threadIdx.x;
  int b = blockIdx.x;

  int e = b * 256 + tid;
  int rk = atomicAdd(&deg[ei[e]], 1);

  int wave = tid >> 6, lane = tid & 63;
  int quad = lane >> 4, c16 = lane & 15;
  int n0 = b * 16;
  int node = n0 + c16;
  // B-fragment = x^T: lane holds x[node=c16][fin = quad*8 + j]
  const float* xp = x + (size_t)node * 32 + quad * 8;
  float4 a0 = *reinterpret_cast<const float4*>(xp);
  float4 a1 = *reinterpret_cast<const float4*>(xp + 4);
  short8 af;
  af[0] = (short)f32_to_bf16(a0.x); af[1] = (short)f32_to_bf16(a0.y);
  af[2] = (short)f32_to_bf16(a0.z); af[3] = (short)f32_to_bf16(a0.w);
  af[4] = (short)f32_to_bf16(a1.x); af[5] = (short)f32_to_bf16(a1.y);
  af[6] = (short)f32_to_bf16(a1.z); af[7] = (short)f32_to_bf16(a1.w);

  float rsum = 0.f;
  for (int idx = 0; idx < 13; idx++) {
    int t = wave * 13 + idx;
    // A-fragment: lane holds A[row=c16][k=quad*8+j]
    short8 bf = *reinterpret_cast<const short8*>(wbf + ((t * 4 + quad) * 16 + c16) * 8);
    float4v acc = {0.f, 0.f, 0.f, 0.f};
    acc = __builtin_amdgcn_mfma_f32_16x16x32_bf16(bf, af, acc, 0, 0, 0);
    // D: col=lane&15=node, row=quad*4+r = fo_local
    if (t < 50) {
      uint2 pk;
      pk.x = (unsigned int)f32_to_bf16(acc[0]) |
             ((unsigned int)f32_to_bf16(acc[1]) << 16);
      pk.y = (unsigned int)f32_to_bf16(acc[2]) |
             ((unsigned int)f32_to_bf16(acc[3]) << 16);
      int tq = t * 4 + quad;
      st[tq * 16 + (c16 ^ (tq & 15))] = pk;
    } else {               // wave 3 only: tiles 50,51
      int gfo = (t - 50) * 16 + quad * 4;
      float4 bi = *reinterpret_cast<const float4*>(bias + gfo);
      float4 o;
      o.x = acc[0] + bi.x; o.y = acc[1] + bi.y;
      o.z = acc[2] + bi.z; o.w = acc[3] + bi.w;
      *reinterpret_cast<float4*>(out + (size_t)node * 32 + gfo) = o;
      float4 aw = *reinterpret_cast<const float4*>(att_w + gfo);
      rsum += acc[0] * aw.x + acc[1] * aw.y + acc[2] * aw.z + acc[3] * aw.w;
    }
  }
  if (wave == 3) {   // wave 3 owned both root tiles -> full r_dot
    rsum += __shfl_xor(rsum, 16);
    rsum += __shfl_xor(rsum, 32);
    if (lane < 16) od[node].y = __float_as_uint(rsum);
  }
  __syncthreads();
  // copy-out: dst is 3200 CONSECUTIVE uint2 (block writes 25.6 KB linear)
  uint2* dst = reinterpret_cast<uint2*>(xw) + (size_t)n0 * 200;
  for (int j = tid; j < 3200; j += 256) {
    int nd = j / 200;
    int tq = j - nd * 200;
    dst[j] = st[tq * 16 + (nd ^ (tq & 15))];
  }
  rank[e] = (unsigned short)rk;
}

// ---------------------------------------------------------------------------
// 3-kernel exclusive scan of deg -> offs.
// ---------------------------------------------------------------------------
__global__ __launch_bounds__(256) void kscan1(const int* __restrict__ deg,
                                              int* __restrict__ incl,
                                              int* __restrict__ bsum) {
  __shared__ int s[256];
  int tid = threadIdx.x;
  int i = blockIdx.x * 256 + tid;
  int v = (i < N_NODES) ? deg[i] : 0;
  s[tid] = v;
  __syncthreads();
  for (int d = 1; d < 256; d <<= 1) {
    int t = (tid >= d) ? s[tid - d] : 0;
    __syncthreads();
    s[tid] += t;
    __syncthreads();
  }
  if (i < N_NODES) incl[i] = s[tid];
  if (tid == 255) bsum[blockIdx.x] = s[255];
}

__global__ __launch_bounds__(512) void kscan2(const int* __restrict__ bsum,
                                              int* __restrict__ bbase) {
  __shared__ int s[512];
  int tid = threadIdx.x;
  int v = (tid < NBLK_SCAN) ? bsum[tid] : 0;
  s[tid] = v;
  __syncthreads();
  for (int d = 1; d < 512; d <<= 1) {
    int t = (tid >= d) ? s[tid - d] : 0;
    __syncthreads();
    s[tid] += t;
    __syncthreads();
  }
  if (tid < NBLK_SCAN) bbase[tid] = s[tid] - v;  // exclusive
}

__global__ __launch_bounds__(256) void kscan3(const int* __restrict__ deg,
                                              int* __restrict__ offs,
                                              const int* __restrict__ bbase,
                                              uint2* __restrict__ od) {
  int i = blockIdx.x * 256 + threadIdx.x;
  if (i < N_NODES) {
    int v = offs[i] - deg[i] + bbase[i >> 8];
    offs[i] = v;
    od[i].x = (unsigned int)v;   // pack exclusive offset next to r_dot bits
  }
  if (i == 0) {
    offs[N_NODES] = N_EDGES;
    od[N_NODES].x = (unsigned int)N_EDGES;   // k2 reads od[node+1].x
  }
}

// ---------------------------------------------------------------------------
// K_scatter: 1 edge/thread, 6250 blocks — pos = offs[row] + rank[e]
// (deterministic; round-8 mechanism). ONE 8B packet per edge:
//   epack.x = col*800 + w0*32  (direct xw element offset; w0 = i0+5*i1 <= 18,
//             so max offset 79,999,999 < 80M — no pad row needed.
//             w1 = +32, w2 = +160, w3 = +192 in elements.)
//   epack.y = fr0_q16 | fr1_q16<<16
// ---------------------------------------------------------------------------
__global__ __launch_bounds__(256) void kscatter(
    const int* __restrict__ ei, const float* __restrict__ pseudo,
    const uint2* __restrict__ od, const unsigned short* __restrict__ rank,
    uint2* __restrict__ epack) {
  int e = blockIdx.x * 256 + threadIdx.x;
  int r = ei[e];
  int c = ei[N_EDGES + e];
  float p0 = pseudo[2 * e] * 4.f;
  float p1 = pseudo[2 * e + 1] * 4.f;
  int rk = rank[e];
  unsigned int offr = od[r].x;      // one random 8B line (800KB, L2-friendly)
  float fl0 = floorf(p0), fl1 = floorf(p1);
  float fr0 = p0 - fl0, fr1 = p1 - fl1;
  int i0 = (int)fl0, i1 = (int)fl1;
  int w0 = i0 + 5 * i1;
  unsigned int q0 = (unsigned int)(fr0 * 65535.f + 0.5f);
  unsigned int q1 = (unsigned int)(fr1 * 65535.f + 0.5f);
  uint2 pk;
  pk.x = (unsigned int)(c * 800 + w0 * 32);
  pk.y = q0 | (q1 << 16);
  epack[offr + rk] = pk;
}

// ---------------------------------------------------------------------------
// K2: one wave per node; halves process alternate edges (lane=f_out);
// 4-deep unroll per half. alpha inline: msg from 4 xw gathers at
// base[0],[32],[160],[192] (offset precomputed in epack.x — zero decode
// arithmetic), t = msg.att2 via 5-step shfl_xor reduce, leaky-relu + exp,
// acc += msg*ex, den += ex. Reads {offs, r_dot} from packed od.
// ---------------------------------------------------------------------------
__global__ __launch_bounds__(256) void k2_csr(
    const uint2* __restrict__ od, const uint2* __restrict__ epack,
    const unsigned short* __restrict__ xw, const float* __restrict__ att_w,
    float* __restrict__ out) {
  int tid = threadIdx.x;
  int wave = tid >> 6, lane = tid & 63;
  int node = blockIdx.x * 4 + wave;
  if (node >= N_NODES) return;
  int f = lane & 31, half = lane >> 5;
  uint2 v0 = od[node];
  int s0 = (int)v0.x;
  int s1 = (int)od[node + 1].x;
  float rd = __uint_as_float(v0.y);
  float a2 = att_w[32 + f];
  const unsigned short* xwf = xw + f;
  float acc = 0.f, den = 0.f;
  int i = s0 + half;
  const float Q = 1.f / 65535.f;

  for (; i + 6 < s1; i += 8) {
    uint2 p[4];
    p[0] = epack[i];     p[1] = epack[i + 2];
    p[2] = epack[i + 4]; p[3] = epack[i + 6];
    float fr0[4], fr1[4];
#pragma unroll
    for (int u = 0; u < 4; u++) {
      fr0[u] = (float)(p[u].y & 0xffff) * Q;
      fr1[u] = (float)(p[u].y >> 16) * Q;
    }
    float g0[4], g1[4], g2[4], g3[4];
#pragma unroll
    for (int u = 0; u < 4; u++) {
      const unsigned short* base = xwf + p[u].x;
      g0[u] = bf16_to_f32(base[0]);
      g1[u] = bf16_to_f32(base[32]);
      g2[u] = bf16_to_f32(base[160]);
      g3[u] = bf16_to_f32(base[192]);
    }
    float msg[4], t[4];
#pragma unroll
    for (int u = 0; u < 4; u++) {
      float c0 = 1.f - fr0[u], c1 = 1.f - fr1[u];
      msg[u] = c1 * (c0 * g0[u] + fr0[u] * g1[u]) +
               fr1[u] * (c0 * g2[u] + fr0[u] * g3[u]);
      t[u] = msg[u] * a2;
    }
#pragma unroll
    for (int m = 16; m >= 1; m >>= 1) {
      t[0] += __shfl_xor(t[0], m);
      t[1] += __shfl_xor(t[1], m);
      t[2] += __shfl_xor(t[2], m);
      t[3] += __shfl_xor(t[3], m);
    }
#pragma unroll
    for (int u = 0; u < 4; u++) {
      float alpha = rd + t[u];
      alpha = alpha > 0.f ? alpha : 0.2f * alpha;
      float ex = __expf(alpha);
      acc += msg[u] * ex;
      den += ex;
    }
  }
  for (; i < s1; i += 2) {
    uint2 pv = epack[i];
    float fr0 = (float)(pv.y & 0xffff) * Q;
    float fr1 = (float)(pv.y >> 16) * Q;
    const unsigned short* base = xwf + pv.x;
    float g0 = bf16_to_f32(base[0]);
    float g1 = bf16_to_f32(base[32]);
    float g2 = bf16_to_f32(base[160]);
    float g3 = bf16_to_f32(base[192]);
    float c0 = 1.f - fr0, c1 = 1.f - fr1;
    float msg = c1 * (c0 * g0 + fr0 * g1) + fr1 * (c0 * g2 + fr0 * g3);
    float t = msg * a2;
#pragma unroll
    for (int m = 16; m >= 1; m >>= 1) t += __shfl_xor(t, m);
    float alpha = rd + t;
    alpha = alpha > 0.f ? alpha : 0.2f * alpha;
    float ex = __expf(alpha);
    acc += msg * ex;
    den += ex;
  }

  acc += __shfl_xor(acc, 32);
  den += __shfl_xor(den, 32);
  if (half == 0) out[node * 32 + f] += acc / (den + 1e-16f);
}

extern "C" void kernel_launch(void* const* d_in, const int* in_sizes, int n_in,
                              void* d_out, int out_size, void* d_ws, size_t ws_size,
                              hipStream_t stream) {
  const float* x      = (const float*)d_in[0];
  const int*   ei     = (const int*)d_in[1];
  const float* pseudo = (const float*)d_in[2];
  const float* weight = (const float*)d_in[3];
  const float* root_w = (const float*)d_in[4];
  const float* att_w  = (const float*)d_in[5];
  const float* bias   = (const float*)d_in[6];
  float* out = (float*)d_out;

  char* ws = (char*)d_ws;
  unsigned short* xw   = (unsigned short*)ws;                 // 160,000,000 B
  uint2* od            = (uint2*)(ws + 160000000);            //     800,016 B {offs, r_dot} x (N+1)
  unsigned short* wbf  = (unsigned short*)(ws + 160800016);   //      53,248 B (52 tiles)
  int* deg             = (int*)(ws + 160853264);              //     400,000 B
  int* offs            = (int*)(ws + 161253264);              //     400,016 B
  int* bsum            = (int*)(ws + 161653280);              //       1,600 B
  int* bbase           = (int*)(ws + 161654880);              //       1,600 B
  unsigned short* rank = (unsigned short*)(ws + 161656480);   //   3,200,000 B
  uint2* epack         = (uint2*)(ws + 164856480);            //  12,800,000 B -> 177.66 MB

  hipLaunchKernelGGL(k_zero, dim3(NBLK_SCAN), dim3(256), 0, stream,
                     weight, root_w, deg, wbf);
  hipLaunchKernelGGL(k1_xw, dim3(6250), dim3(256), 0, stream,
                     x, wbf, ei, att_w, bias, deg, rank, xw, out, od);
  hipLaunchKernelGGL(kscan1, dim3(NBLK_SCAN), dim3(256), 0, stream, deg, offs, bsum);
  hipLaunchKernelGGL(kscan2, dim3(1), dim3(512), 0, stream, bsum, bbase);
  hipLaunchKernelGGL(kscan3, dim3(NBLK_SCAN), dim3(256), 0, stream,
                     deg, offs, bbase, od);
  hipLaunchKernelGGL(kscatter, dim3(6250), dim3(256), 0, stream,
                     ei, pseudo, od, rank, epack);
  hipLaunchKernelGGL(k2_csr, dim3(25000), dim3(256), 0, stream,
                     od, epack, xw, att_w, out);
}